// Round 6
// baseline (94.733 us; speedup 1.0000x reference)
//
#include <hip/hip_runtime.h>
#include <math.h>

// Problem constants (from reference)
#define BATCH    512
#define N_VARS   4096
#define H_ROWS   (2 * N_VARS + 2)   // 8194
#define N_OUT1   8192
#define N_OUT3   2048
#define TPB      1024
#define SMEM_BYTES (H_ROWS * sizeof(float2))   // 65552 B — needs dynamic LDS

// Fast native-transcendental variants. Accuracy budget: threshold 0.38,
// exact-math absmax was 0.0625; these add <~1e-3.
__device__ __forceinline__ float log1mexp_fast(float x) {
    return __logf(1.0f - __expf(x));
}

__device__ __forceinline__ float2 lse2_fast2(float2 a, float2 b) {
    float2 r;
    r.x = fmaxf(a.x, b.x) + __logf(1.0f + __expf(-fabsf(a.x - b.x)));
    r.y = fmaxf(a.y, b.y) + __logf(1.0f + __expf(-fabsf(a.y - b.y)));
    return r;
}

// Fuse the two-level gather (sum ptrs -> product ptrs) into index tables for
// both sum layers in ONE kernel. tab[2*o], tab[2*o+1] = 8 source rows of o.
__global__ void build_tabs_kernel(const int* __restrict__ p0,
                                  const int* __restrict__ p1,
                                  const int* __restrict__ p2,
                                  const int* __restrict__ p3,
                                  int4* __restrict__ tabB,
                                  int4* __restrict__ tabC) {
    int o = blockIdx.x * blockDim.x + threadIdx.x;
    if (o < N_OUT1) {
        int2 pp = ((const int2*)p1)[o];
        tabB[2 * o]     = ((const int4*)p0)[pp.x];
        tabB[2 * o + 1] = ((const int4*)p0)[pp.y];
    } else {
        int oc = o - N_OUT1;   // N_OUT3 outputs
        int2 pp = ((const int2*)p3)[oc];
        tabC[2 * oc]     = ((const int4*)p2)[pp.x];
        tabC[2 * oc + 1] = ((const int4*)p2)[pp.y];
    }
}

// TWO adjacent batch columns per workgroup; LDS buf is float2 (.x = col b0,
// .y = col b1 = b0+1). Adjacency makes x reads and out writes aligned 8 B
// accesses directly in the reference layouts — no transpose kernels at all.
// All random gathers are ds_read_b64 serving both columns at once.
__global__ void __launch_bounds__(TPB, 4)
fused_spn_kernel(const float* __restrict__ x,
                 const int4* __restrict__ tabB,
                 const int4* __restrict__ tabC,
                 float* __restrict__ out) {
    extern __shared__ float2 buf[];   // H_ROWS entries
    const int bp = blockIdx.x;        // column pair: columns 2*bp, 2*bp+1
    const int t = threadIdx.x;
    const float2* x2 = (const float2*)x;     // [N_VARS][BATCH/2]

    // ---- Phase A: encode. 8 B load per var for this column pair; one
    //      contiguous 16 B LDS write per var (buf[2i+2], buf[2i+3]). ----
    if (t == 0) {
        buf[0] = make_float2(-INFINITY, -INFINITY);
        buf[1] = make_float2(0.f, 0.f);
    }
#pragma unroll
    for (int k = 0; k < N_VARS / TPB; ++k) {
        int i = t + k * TPB;
        float2 p = x2[(size_t)i * (BATCH / 2) + bp];
        buf[2 * i + 2] = p;
        buf[2 * i + 3] = make_float2(log1mexp_fast(p.x), log1mexp_fast(p.y));
    }
    __syncthreads();

    // ---- Phase B: product(4)+lse(2) -> out1 regs, chunked 4-wide for MLP ----
    float2 r1[N_OUT1 / TPB];   // 8 per thread
#pragma unroll
    for (int c = 0; c < N_OUT1 / TPB; c += 4) {
        int4 qa[4], qb[4];
#pragma unroll
        for (int k = 0; k < 4; ++k) {
            int o = t + (c + k) * TPB;
            qa[k] = tabB[2 * o];
            qb[k] = tabB[2 * o + 1];
        }
#pragma unroll
        for (int k = 0; k < 4; ++k) {
            float2 va0 = buf[qa[k].x], va1 = buf[qa[k].y];
            float2 va2 = buf[qa[k].z], va3 = buf[qa[k].w];
            float2 vb0 = buf[qb[k].x], vb1 = buf[qb[k].y];
            float2 vb2 = buf[qb[k].z], vb3 = buf[qb[k].w];
            float2 ga = make_float2(va0.x + va1.x + va2.x + va3.x,
                                    va0.y + va1.y + va2.y + va3.y);
            float2 gb = make_float2(vb0.x + vb1.x + vb2.x + vb3.x,
                                    vb0.y + vb1.y + vb2.y + vb3.y);
            r1[c + k] = lse2_fast2(ga, gb);
        }
    }
    __syncthreads();
#pragma unroll
    for (int k = 0; k < N_OUT1 / TPB; ++k)
        buf[t + k * TPB] = r1[k];
    __syncthreads();

    // ---- Phase C: product(4)+lse(2) -> out[o][b0..b1] (aligned 8 B store) ----
    {
        int4 qa[2], qb[2];
#pragma unroll
        for (int k = 0; k < 2; ++k) {
            int o = t + k * TPB;
            qa[k] = tabC[2 * o];
            qb[k] = tabC[2 * o + 1];
        }
#pragma unroll
        for (int k = 0; k < 2; ++k) {
            int o = t + k * TPB;
            float2 va0 = buf[qa[k].x], va1 = buf[qa[k].y];
            float2 va2 = buf[qa[k].z], va3 = buf[qa[k].w];
            float2 vb0 = buf[qb[k].x], vb1 = buf[qb[k].y];
            float2 vb2 = buf[qb[k].z], vb3 = buf[qb[k].w];
            float2 ga = make_float2(va0.x + va1.x + va2.x + va3.x,
                                    va0.y + va1.y + va2.y + va3.y);
            float2 gb = make_float2(vb0.x + vb1.x + vb2.x + vb3.x,
                                    vb0.y + vb1.y + vb2.y + vb3.y);
            ((float2*)(out + (size_t)o * BATCH))[bp] = lse2_fast2(ga, gb);
        }
    }
}

extern "C" void kernel_launch(void* const* d_in, const int* in_sizes, int n_in,
                              void* d_out, int out_size, void* d_ws, size_t ws_size,
                              hipStream_t stream) {
    const float* x     = (const float*)d_in[0];
    const int*   ptrs0 = (const int*)d_in[1];
    const int*   ptrs1 = (const int*)d_in[3];
    const int*   ptrs2 = (const int*)d_in[5];
    const int*   ptrs3 = (const int*)d_in[7];
    float* out = (float*)d_out;

    int4* tabB = (int4*)d_ws;              // 8192*2 int4 (256 KB)
    int4* tabC = tabB + 2 * N_OUT1;        // 2048*2 int4 (64 KB)

    // Allow >64 KB dynamic LDS for the fused kernel (gfx950: 160 KB/WG max).
    // Unconditional each call: same work every launch (graph-capture rule).
    hipFuncSetAttribute((const void*)fused_spn_kernel,
                        hipFuncAttributeMaxDynamicSharedMemorySize, SMEM_BYTES);

    // Precompute fused gather tables (ptrs are batch-invariant).
    build_tabs_kernel<<<(N_OUT1 + N_OUT3) / 256, 256, 0, stream>>>(
        ptrs0, ptrs1, ptrs2, ptrs3, tabB, tabC);

    fused_spn_kernel<<<BATCH / 2, TPB, SMEM_BYTES, stream>>>(x, tabB, tabC, out);
}

// Round 7
// 89.089 us; speedup vs baseline: 1.0634x; 1.0634x over previous
//
#include <hip/hip_runtime.h>
#include <math.h>

// Problem constants (from reference)
#define BATCH    512
#define N_VARS   4096
#define H_ROWS   (2 * N_VARS + 2)   // 8194
#define N_OUT1   8192
#define N_OUT3   2048
#define TPB      1024
#define SMEM_BYTES (H_ROWS * sizeof(float2))   // 65552 B — needs dynamic LDS

// Fast native-transcendental variants. Accuracy budget: threshold 0.38,
// exact-math absmax was 0.0625; these add <~1e-3.
__device__ __forceinline__ float log1mexp_fast(float x) {
    return __logf(1.0f - __expf(x));
}

__device__ __forceinline__ float2 lse2_fast2(float2 a, float2 b) {
    float2 r;
    r.x = fmaxf(a.x, b.x) + __logf(1.0f + __expf(-fabsf(a.x - b.x)));
    r.y = fmaxf(a.y, b.y) + __logf(1.0f + __expf(-fabsf(a.y - b.y)));
    return r;
}

// ---- Prep kernel: x-transpose AND fused gather-table build in ONE dispatch.
// blocks [0, NTRANS): 32x32 tiled transpose x[4096][512] -> xT[512][4096]
// blocks [NTRANS, NTRANS+NTAB): tab build (flat 256 threads/block)
#define TDIM    32
#define NTRANS  ((BATCH / TDIM) * (N_VARS / TDIM))   // 16 * 128 = 2048
#define NTAB    ((N_OUT1 + N_OUT3) / 256)            // 40
__global__ void prep_kernel(const float* __restrict__ x,
                            float* __restrict__ xT,
                            const int* __restrict__ p0,
                            const int* __restrict__ p1,
                            const int* __restrict__ p2,
                            const int* __restrict__ p3,
                            int4* __restrict__ tabB,
                            int4* __restrict__ tabC) {
    __shared__ float tile[TDIM][TDIM + 1];
    int blk = blockIdx.x;
    int tx = threadIdx.x, ty = threadIdx.y;
    if (blk < NTRANS) {
        // transpose: R=N_VARS rows, C=BATCH cols; grid laid out (C/32, R/32)
        int cb = (blk % (BATCH / TDIM)) * TDIM;
        int rb = (blk / (BATCH / TDIM)) * TDIM;
#pragma unroll
        for (int j = 0; j < TDIM; j += 8)
            tile[ty + j][tx] = x[(size_t)(rb + ty + j) * BATCH + cb + tx];
        __syncthreads();
#pragma unroll
        for (int j = 0; j < TDIM; j += 8)
            xT[(size_t)(cb + ty + j) * N_VARS + rb + tx] = tile[tx][ty + j];
    } else {
        int o = (blk - NTRANS) * 256 + ty * TDIM + tx;
        if (o < N_OUT1) {
            int2 pp = ((const int2*)p1)[o];
            tabB[2 * o]     = ((const int4*)p0)[pp.x];
            tabB[2 * o + 1] = ((const int4*)p0)[pp.y];
        } else {
            int oc = o - N_OUT1;
            int2 pp = ((const int2*)p3)[oc];
            tabC[2 * oc]     = ((const int4*)p2)[pp.x];
            tabC[2 * oc + 1] = ((const int4*)p2)[pp.y];
        }
    }
}

// TWO adjacent batch columns per workgroup; LDS buf is float2 (.x = col b0,
// .y = col b1). Reads xT rows (coalesced float4); random gathers are
// ds_read_b64 serving both columns; out stored directly (8 B/thread,
// fire-and-forget). 65552 B dynamic LDS, 256 blocks = 1/CU, 16 waves.
__global__ void __launch_bounds__(TPB, 4)
fused_spn_kernel(const float* __restrict__ xT,
                 const int4* __restrict__ tabB,
                 const int4* __restrict__ tabC,
                 float* __restrict__ out) {
    extern __shared__ float2 buf[];   // H_ROWS entries
    const int bp = blockIdx.x;        // columns 2*bp, 2*bp+1
    const int t = threadIdx.x;

    // ---- Phase A: encode. Coalesced float4 loads of xT rows b0,b1;
    //      contiguous 64 B LDS write per thread (buf[8t+2 .. 8t+9]). ----
    if (t == 0) {
        buf[0] = make_float2(-INFINITY, -INFINITY);
        buf[1] = make_float2(0.f, 0.f);
    }
    {
        float4 pa = ((const float4*)(xT + (size_t)(2 * bp)     * N_VARS))[t];
        float4 pb = ((const float4*)(xT + (size_t)(2 * bp + 1) * N_VARS))[t];
        int base = 8 * t + 2;
        buf[base + 0] = make_float2(pa.x, pb.x);
        buf[base + 1] = make_float2(log1mexp_fast(pa.x), log1mexp_fast(pb.x));
        buf[base + 2] = make_float2(pa.y, pb.y);
        buf[base + 3] = make_float2(log1mexp_fast(pa.y), log1mexp_fast(pb.y));
        buf[base + 4] = make_float2(pa.z, pb.z);
        buf[base + 5] = make_float2(log1mexp_fast(pa.z), log1mexp_fast(pb.z));
        buf[base + 6] = make_float2(pa.w, pb.w);
        buf[base + 7] = make_float2(log1mexp_fast(pa.w), log1mexp_fast(pb.w));
    }
    __syncthreads();

    // ---- Phase B: product(4)+lse(2) -> out1 regs, chunked 4-wide for MLP ----
    float2 r1[N_OUT1 / TPB];   // 8 per thread
#pragma unroll
    for (int c = 0; c < N_OUT1 / TPB; c += 4) {
        int4 qa[4], qb[4];
#pragma unroll
        for (int k = 0; k < 4; ++k) {
            int o = t + (c + k) * TPB;
            qa[k] = tabB[2 * o];
            qb[k] = tabB[2 * o + 1];
        }
#pragma unroll
        for (int k = 0; k < 4; ++k) {
            float2 va0 = buf[qa[k].x], va1 = buf[qa[k].y];
            float2 va2 = buf[qa[k].z], va3 = buf[qa[k].w];
            float2 vb0 = buf[qb[k].x], vb1 = buf[qb[k].y];
            float2 vb2 = buf[qb[k].z], vb3 = buf[qb[k].w];
            float2 ga = make_float2(va0.x + va1.x + va2.x + va3.x,
                                    va0.y + va1.y + va2.y + va3.y);
            float2 gb = make_float2(vb0.x + vb1.x + vb2.x + vb3.x,
                                    vb0.y + vb1.y + vb2.y + vb3.y);
            r1[c + k] = lse2_fast2(ga, gb);
        }
    }
    __syncthreads();
#pragma unroll
    for (int k = 0; k < N_OUT1 / TPB; ++k)
        buf[t + k * TPB] = r1[k];
    __syncthreads();

    // ---- Phase C: product(4)+lse(2) -> out[o][2bp..2bp+1] (8 B store) ----
    {
        int4 qa[2], qb[2];
#pragma unroll
        for (int k = 0; k < 2; ++k) {
            int o = t + k * TPB;
            qa[k] = tabC[2 * o];
            qb[k] = tabC[2 * o + 1];
        }
#pragma unroll
        for (int k = 0; k < 2; ++k) {
            int o = t + k * TPB;
            float2 va0 = buf[qa[k].x], va1 = buf[qa[k].y];
            float2 va2 = buf[qa[k].z], va3 = buf[qa[k].w];
            float2 vb0 = buf[qb[k].x], vb1 = buf[qb[k].y];
            float2 vb2 = buf[qb[k].z], vb3 = buf[qb[k].w];
            float2 ga = make_float2(va0.x + va1.x + va2.x + va3.x,
                                    va0.y + va1.y + va2.y + va3.y);
            float2 gb = make_float2(vb0.x + vb1.x + vb2.x + vb3.x,
                                    vb0.y + vb1.y + vb2.y + vb3.y);
            ((float2*)(out + (size_t)o * BATCH))[bp] = lse2_fast2(ga, gb);
        }
    }
}

extern "C" void kernel_launch(void* const* d_in, const int* in_sizes, int n_in,
                              void* d_out, int out_size, void* d_ws, size_t ws_size,
                              hipStream_t stream) {
    const float* x     = (const float*)d_in[0];
    const int*   ptrs0 = (const int*)d_in[1];
    const int*   ptrs1 = (const int*)d_in[3];
    const int*   ptrs2 = (const int*)d_in[5];
    const int*   ptrs3 = (const int*)d_in[7];
    float* out = (float*)d_out;

    float* xT  = (float*)d_ws;                          // 4096*512 floats (8 MB)
    int4*  tabB = (int4*)(xT + (size_t)N_VARS * BATCH); // 8192*2 int4 (256 KB)
    int4*  tabC = tabB + 2 * N_OUT1;                    // 2048*2 int4 (64 KB)

    // Allow >64 KB dynamic LDS (gfx950: 160 KB/WG). Unconditional each call.
    hipFuncSetAttribute((const void*)fused_spn_kernel,
                        hipFuncAttributeMaxDynamicSharedMemorySize, SMEM_BYTES);

    prep_kernel<<<NTRANS + NTAB, dim3(32, 8), 0, stream>>>(
        x, xT, ptrs0, ptrs1, ptrs2, ptrs3, tabB, tabC);

    fused_spn_kernel<<<BATCH / 2, TPB, SMEM_BYTES, stream>>>(xT, tabB, tabC, out);
}